// Round 1
// baseline (219.698 us; speedup 1.0000x reference)
//
#include <hip/hip_runtime.h>
#include <stdint.h>

// Problem constants: B=2, S=2048, E=1024, H=16, D=64, M = B*S = 4096
#define LOG2E 1.4426950408889634f

using u16 = unsigned short;
using u32 = unsigned int;

typedef __attribute__((ext_vector_type(8))) short short8;
typedef __attribute__((ext_vector_type(4))) float f32x4;

__device__ __forceinline__ u16 f32_bf16(float f) {
  union { float f; u32 u; } v; v.f = f;
  u32 u = v.u;
  u += 0x7FFF + ((u >> 16) & 1);   // RNE
  return (u16)(u >> 16);
}

__device__ __forceinline__ void gload_lds16(const void* g, void* l) {
  __builtin_amdgcn_global_load_lds(
      (const __attribute__((address_space(1))) u32*)(uintptr_t)g,
      (__attribute__((address_space(3))) u32*)(u32)(uintptr_t)l, 16, 0, 0);
}

// ---------------- pre-passes ----------------

__global__ __launch_bounds__(256) void cvt_f32_bf16(const float* __restrict__ in,
                                                    u16* __restrict__ out, int n4) {
  for (int i = blockIdx.x * blockDim.x + threadIdx.x; i < n4;
       i += gridDim.x * blockDim.x) {
    float4 v = ((const float4*)in)[i];
    union { u16 h[4]; uint2 u; } o;
    o.h[0] = f32_bf16(v.x); o.h[1] = f32_bf16(v.y);
    o.h[2] = f32_bf16(v.z); o.h[3] = f32_bf16(v.w);
    ((uint2*)out)[i] = o.u;
  }
}

// out[n][k] = bf16(in[k][n]);  in is [K][N] fp32 row-major
__global__ __launch_bounds__(256) void transpose_bf16(const float* __restrict__ in,
                                                      u16* __restrict__ out,
                                                      int K, int N) {
  __shared__ float t[32][33];
  const int n0 = blockIdx.x * 32, k0 = blockIdx.y * 32;
  const int tx = threadIdx.x, ty = threadIdx.y;
#pragma unroll
  for (int j = 0; j < 32; j += 8)
    t[ty + j][tx] = in[(size_t)(k0 + ty + j) * N + n0 + tx];
  __syncthreads();
#pragma unroll
  for (int j = 0; j < 32; j += 8)
    out[(size_t)(n0 + ty + j) * K + k0 + tx] = f32_bf16(t[tx][ty + j]);
}

// ---------------- GEMM: C = A[M,K] * Bt[N,K]^T + bias ----------------
// 128x128 tile, 4 waves (2x2), BK=32, global_load_lds staging (m97 structure).
// MODE 0: QKV epilogue -> scatter to Q[B,H,S,D]*0.125, K[B,H,S,D], Vt[B,H,D,S] (bf16)
// MODE 1: fp32 out + bias to fout[M,1024]
template <int MODE>
__global__ __launch_bounds__(256) void gemm_bt(
    const u16* __restrict__ A, const u16* __restrict__ Bt,
    const float* __restrict__ bias,
    u16* __restrict__ qb, u16* __restrict__ kb, u16* __restrict__ vtb,
    float* __restrict__ fout) {
  __shared__ u16 lA[128 * 32];
  __shared__ u16 lB[128 * 32];
  const int tid = threadIdx.x;
  const int w = tid >> 6, l = tid & 63;
  const int bm = blockIdx.y, bn = blockIdx.x;
  const size_t m0 = (size_t)bm * 128, n0 = (size_t)bn * 128;
  const int wr = w >> 1, wc = w & 1;

  f32x4 acc[4][4] = {};

  const int arow = w * 16 + (l >> 2);
  const int acol = (l & 3) * 8;
  const u16* gA = A + (m0 + arow) * 1024 + acol;
  const u16* gB = Bt + (n0 + arow) * 1024 + acol;
  u16* lAw = lA + w * 512;  // HW adds lane*16B
  u16* lBw = lB + w * 512;

  for (int k0 = 0; k0 < 1024; k0 += 32) {
    gload_lds16(gA + k0, lAw);
    gload_lds16(gA + k0 + 64 * 1024, lAw + 2048);
    gload_lds16(gB + k0, lBw);
    gload_lds16(gB + k0 + 64 * 1024, lBw + 2048);
    __syncthreads();
    short8 af[4], bf[4];
#pragma unroll
    for (int m = 0; m < 4; ++m)
      af[m] = *(const short8*)&lA[(wr * 64 + m * 16 + (l & 15)) * 32 + (l >> 4) * 8];
#pragma unroll
    for (int n = 0; n < 4; ++n)
      bf[n] = *(const short8*)&lB[(wc * 64 + n * 16 + (l & 15)) * 32 + (l >> 4) * 8];
#pragma unroll
    for (int m = 0; m < 4; ++m)
#pragma unroll
      for (int n = 0; n < 4; ++n)
        acc[m][n] = __builtin_amdgcn_mfma_f32_16x16x32_bf16(af[m], bf[n], acc[m][n], 0, 0, 0);
    __syncthreads();
  }

  if (MODE == 0) {
#pragma unroll
    for (int m = 0; m < 4; ++m) {
      const int row = (int)m0 + wr * 64 + m * 16 + ((l >> 4) << 2);
      const int b = row >> 11, s = row & 2047;
#pragma unroll
      for (int n = 0; n < 4; ++n) {
        const int col = (int)n0 + wc * 64 + n * 16 + (l & 15);
        const int part = col >> 10;
        const int h = (col & 1023) >> 6, d = col & 63;
        const float bv = bias[col];
        const size_t bh = (size_t)(b * 16 + h);
#pragma unroll
        for (int r = 0; r < 4; ++r) {
          const float v = acc[m][n][r] + bv;
          const int ss = s + r;
          if (part == 0)
            qb[(bh * 2048 + ss) * 64 + d] = f32_bf16(v * 0.125f);  // fold 1/sqrt(64)
          else if (part == 1)
            kb[(bh * 2048 + ss) * 64 + d] = f32_bf16(v);
          else
            vtb[(bh * 64 + d) * 2048 + ss] = f32_bf16(v);  // V transposed
        }
      }
    }
  } else {
#pragma unroll
    for (int m = 0; m < 4; ++m) {
      const size_t row = m0 + wr * 64 + m * 16 + ((l >> 4) << 2);
#pragma unroll
      for (int n = 0; n < 4; ++n) {
        const size_t col = n0 + wc * 64 + n * 16 + (l & 15);
        const float bv = bias[col];
#pragma unroll
        for (int r = 0; r < 4; ++r)
          fout[(row + r) * 1024 + col] = acc[m][n][r] + bv;
      }
    }
  }
}

// ---------------- causal flash attention ----------------
// grid: (B*H, 16). 4 waves x 32 q-rows = 128-row Q tile. KV tile = 64.
// K/V reg-staged into padded LDS (stride 72 elems) -> conflict-free b128 frag reads.
__global__ __launch_bounds__(256) void attn_fwd(const u16* __restrict__ Qb,
                                                const u16* __restrict__ Kb,
                                                const u16* __restrict__ Vt,
                                                u16* __restrict__ AO) {
  __shared__ u16 lK[64 * 72];
  __shared__ u16 lV[64 * 72];
  __shared__ u16 lP[128 * 72];
  const int tid = threadIdx.x, w = tid >> 6, l = tid & 63;
  const int bh = blockIdx.x;
  const int jy = blockIdx.y;
  const int qt = (jy < 8) ? jy : 23 - jy;  // load-balance pairing (sums const)
  const int q0 = qt * 128;
  const u16* Qh = Qb + (size_t)bh * 2048 * 64;
  const u16* Kh = Kb + (size_t)bh * 2048 * 64;
  const u16* Vh = Vt + (size_t)bh * 64 * 2048;

  short8 qf[2][2];
#pragma unroll
  for (int m = 0; m < 2; ++m)
#pragma unroll
    for (int kk = 0; kk < 2; ++kk)
      qf[m][kk] = *(const short8*)&Qh[(size_t)(q0 + w * 32 + m * 16 + (l & 15)) * 64 +
                                      kk * 32 + (l >> 4) * 8];

  f32x4 acc[2][4] = {};
  const float NEG = -3.0e38f;
  float mrow[2][4], lsum[2][4];
#pragma unroll
  for (int m = 0; m < 2; ++m)
#pragma unroll
    for (int r = 0; r < 4; ++r) { mrow[m][r] = NEG; lsum[m][r] = 0.f; }

  const int qrow_base = q0 + w * 32 + ((l >> 4) << 2);
  const int nkt = q0 / 64 + 2;

  for (int kt = 0; kt < nkt; ++kt) {
    // stage K [64 s][64 d] and Vt [64 d][64 s] tiles, padded stride 144B
#pragma unroll
    for (int i = 0; i < 2; ++i) {
      const int flat = i * 4096 + tid * 16;
      const int row = flat >> 7, colb = flat & 127;
      const uint4 kv = *(const uint4*)((const char*)Kh + (size_t)kt * 8192 + flat);
      const uint4 vv = *(const uint4*)((const char*)Vh + (size_t)row * 4096 +
                                       (size_t)kt * 128 + colb);
      *(uint4*)((char*)lK + row * 144 + colb) = kv;
      *(uint4*)((char*)lV + row * 144 + colb) = vv;
    }
    __syncthreads();

    // S = Q K^T  (scale folded into Q)
    f32x4 sc[2][4] = {};
#pragma unroll
    for (int n = 0; n < 4; ++n)
#pragma unroll
      for (int kk = 0; kk < 2; ++kk) {
        const short8 kf = *(const short8*)((const char*)lK +
                            (n * 16 + (l & 15)) * 144 + kk * 64 + (l >> 4) * 16);
        sc[0][n] = __builtin_amdgcn_mfma_f32_16x16x32_bf16(qf[0][kk], kf, sc[0][n], 0, 0, 0);
        sc[1][n] = __builtin_amdgcn_mfma_f32_16x16x32_bf16(qf[1][kk], kf, sc[1][n], 0, 0, 0);
      }

    // causal mask + online softmax (wave-parallel, 16-lane reduce)
    const int kbase = kt * 64 + (l & 15);
#pragma unroll
    for (int m = 0; m < 2; ++m)
#pragma unroll
      for (int r = 0; r < 4; ++r) {
        const int qrow = qrow_base + m * 16 + r;
        float x = NEG;
#pragma unroll
        for (int n = 0; n < 4; ++n) {
          float v = sc[m][n][r];
          v = (kbase + n * 16 <= qrow) ? v : NEG;
          sc[m][n][r] = v;
          x = fmaxf(x, v);
        }
#pragma unroll
        for (int off = 1; off < 16; off <<= 1) x = fmaxf(x, __shfl_xor(x, off));
        const float mn = fmaxf(mrow[m][r], x);
        const float alpha = exp2f((mrow[m][r] - mn) * LOG2E);
        mrow[m][r] = mn;
        float rs = 0.f;
#pragma unroll
        for (int n = 0; n < 4; ++n) {
          const float p = exp2f((sc[m][n][r] - mn) * LOG2E);
          rs += p;
          lP[(w * 32 + m * 16 + ((l >> 4) << 2) + r) * 72 + n * 16 + (l & 15)] = f32_bf16(p);
        }
#pragma unroll
        for (int off = 1; off < 16; off <<= 1) rs += __shfl_xor(rs, off);
        lsum[m][r] = lsum[m][r] * alpha + rs;
#pragma unroll
        for (int nd = 0; nd < 4; ++nd) acc[m][nd][r] *= alpha;
      }

    asm volatile("s_waitcnt lgkmcnt(0)" ::: "memory");  // wave-local P writes visible

    // O += P * V
#pragma unroll
    for (int kk = 0; kk < 2; ++kk) {
      const short8 pf0 = *(const short8*)((const char*)lP +
                          (w * 32 + (l & 15)) * 144 + kk * 64 + (l >> 4) * 16);
      const short8 pf1 = *(const short8*)((const char*)lP +
                          (w * 32 + 16 + (l & 15)) * 144 + kk * 64 + (l >> 4) * 16);
#pragma unroll
      for (int nd = 0; nd < 4; ++nd) {
        const short8 vf = *(const short8*)((const char*)lV +
                            (nd * 16 + (l & 15)) * 144 + kk * 64 + (l >> 4) * 16);
        acc[0][nd] = __builtin_amdgcn_mfma_f32_16x16x32_bf16(pf0, vf, acc[0][nd], 0, 0, 0);
        acc[1][nd] = __builtin_amdgcn_mfma_f32_16x16x32_bf16(pf1, vf, acc[1][nd], 0, 0, 0);
      }
    }
    __syncthreads();
  }

  // epilogue: merged-heads layout AO[b*2048+q][h*64+d]
  const int b = bh >> 4, h = bh & 15;
#pragma unroll
  for (int m = 0; m < 2; ++m)
#pragma unroll
    for (int nd = 0; nd < 4; ++nd)
#pragma unroll
      for (int r = 0; r < 4; ++r) {
        const int qrow = q0 + w * 32 + m * 16 + ((l >> 4) << 2) + r;
        const int col = h * 64 + nd * 16 + (l & 15);
        AO[(size_t)(b * 2048 + qrow) * 1024 + col] = f32_bf16(acc[m][nd][r] / lsum[m][r]);
      }
}

// ---------------- launch ----------------

extern "C" void kernel_launch(void* const* d_in, const int* in_sizes, int n_in,
                              void* d_out, int out_size, void* d_ws, size_t ws_size,
                              hipStream_t stream) {
  const float* hs = (const float*)d_in[0];
  const float* w1 = (const float*)d_in[1];
  const float* b1 = (const float*)d_in[2];
  const float* w2 = (const float*)d_in[3];
  const float* b2 = (const float*)d_in[4];
  float* out = (float*)d_out;

  char* ws = (char*)d_ws;
  u16* Xb  = (u16*)(ws);                    // [4096][1024] bf16   (8 MB)
  u16* W1t = (u16*)(ws + (8ull  << 20));    // [3072][1024] bf16   (6 MB)
  u16* W2t = (u16*)(ws + (14ull << 20));    // [1024][1024] bf16   (2 MB)
  u16* Qb  = (u16*)(ws + (16ull << 20));    // [B,H,S,D] bf16      (8 MB)
  u16* Kb  = (u16*)(ws + (24ull << 20));    // [B,H,S,D] bf16      (8 MB)
  u16* Vtb = (u16*)(ws + (32ull << 20));    // [B,H,D,S] bf16      (8 MB)
  u16* AO  = (u16*)(ws + (40ull << 20));    // [4096][1024] bf16   (8 MB)

  cvt_f32_bf16<<<dim3(2048), dim3(256), 0, stream>>>(hs, Xb, 4096 * 1024 / 4);
  transpose_bf16<<<dim3(96, 32), dim3(32, 8), 0, stream>>>(w1, W1t, 1024, 3072);
  transpose_bf16<<<dim3(32, 32), dim3(32, 8), 0, stream>>>(w2, W2t, 1024, 1024);
  gemm_bt<0><<<dim3(24, 32), dim3(256), 0, stream>>>(Xb, W1t, b1, Qb, Kb, Vtb, nullptr);
  attn_fwd<<<dim3(32, 16), dim3(256), 0, stream>>>(Qb, Kb, Vtb, AO);
  gemm_bt<1><<<dim3(8, 32), dim3(256), 0, stream>>>(AO, W2t, b2, nullptr, nullptr, nullptr, out);
}

// Round 2
// 157.072 us; speedup vs baseline: 1.3987x; 1.3987x over previous
//
#include <hip/hip_runtime.h>
#include <stdint.h>

// Problem constants: B=2, S=2048, E=1024, H=16, D=64, M = B*S = 4096
#define LOG2E 1.4426950408889634f
#define QSCALE (0.125f * LOG2E)   // fold 1/sqrt(64) and log2(e): softmax in exp2 domain

using u16 = unsigned short;
using u32 = unsigned int;

typedef __attribute__((ext_vector_type(8))) short short8;
typedef __attribute__((ext_vector_type(4))) float f32x4;
typedef __attribute__((ext_vector_type(16))) float f32x16;

__device__ __forceinline__ u16 f32_bf16(float f) {
  union { float f; u32 u; } v; v.f = f;
  u32 u = v.u;
  u += 0x7FFF + ((u >> 16) & 1);   // RNE
  return (u16)(u >> 16);
}

__device__ __forceinline__ void gload_lds16(const void* g, void* l) {
  __builtin_amdgcn_global_load_lds(
      (const __attribute__((address_space(1))) u32*)(uintptr_t)g,
      (__attribute__((address_space(3))) u32*)(u32)(uintptr_t)l, 16, 0, 0);
}

// ---------------- pre-passes ----------------

__global__ __launch_bounds__(256) void cvt_f32_bf16(const float* __restrict__ in,
                                                    u16* __restrict__ out, int n4) {
  for (int i = blockIdx.x * blockDim.x + threadIdx.x; i < n4;
       i += gridDim.x * blockDim.x) {
    float4 v = ((const float4*)in)[i];
    union { u16 h[4]; uint2 u; } o;
    o.h[0] = f32_bf16(v.x); o.h[1] = f32_bf16(v.y);
    o.h[2] = f32_bf16(v.z); o.h[3] = f32_bf16(v.w);
    ((uint2*)out)[i] = o.u;
  }
}

// out[n][k] = bf16(in[k][n]);  in is [K][N] fp32 row-major
__global__ __launch_bounds__(256) void transpose_bf16(const float* __restrict__ in,
                                                      u16* __restrict__ out,
                                                      int K, int N) {
  __shared__ float t[32][33];
  const int n0 = blockIdx.x * 32, k0 = blockIdx.y * 32;
  const int tx = threadIdx.x, ty = threadIdx.y;
#pragma unroll
  for (int j = 0; j < 32; j += 8)
    t[ty + j][tx] = in[(size_t)(k0 + ty + j) * N + n0 + tx];
  __syncthreads();
#pragma unroll
  for (int j = 0; j < 32; j += 8)
    out[(size_t)(n0 + ty + j) * K + k0 + tx] = f32_bf16(t[tx][ty + j]);
}

// ---------------- GEMM: C = A[M,K] * Bt[N,K]^T + bias ----------------
// 128x128 tile, 4 waves (2x2), BK=32, global_load_lds staging (m97 structure).
// MODE 0: QKV epilogue -> scatter to Q[B,H,S,D]*QSCALE, K[B,H,S,D], Vt[B,H,D,S] (bf16)
// MODE 1: fp32 out + bias to fout[M,1024]
template <int MODE>
__global__ __launch_bounds__(256) void gemm_bt(
    const u16* __restrict__ A, const u16* __restrict__ Bt,
    const float* __restrict__ bias,
    u16* __restrict__ qb, u16* __restrict__ kb, u16* __restrict__ vtb,
    float* __restrict__ fout) {
  __shared__ u16 lA[128 * 32];
  __shared__ u16 lB[128 * 32];
  const int tid = threadIdx.x;
  const int w = tid >> 6, l = tid & 63;
  const int bm = blockIdx.y, bn = blockIdx.x;
  const size_t m0 = (size_t)bm * 128, n0 = (size_t)bn * 128;
  const int wr = w >> 1, wc = w & 1;

  f32x4 acc[4][4] = {};

  const int arow = w * 16 + (l >> 2);
  const int acol = (l & 3) * 8;
  const u16* gA = A + (m0 + arow) * 1024 + acol;
  const u16* gB = Bt + (n0 + arow) * 1024 + acol;
  u16* lAw = lA + w * 512;  // HW adds lane*16B
  u16* lBw = lB + w * 512;

  for (int k0 = 0; k0 < 1024; k0 += 32) {
    gload_lds16(gA + k0, lAw);
    gload_lds16(gA + k0 + 64 * 1024, lAw + 2048);
    gload_lds16(gB + k0, lBw);
    gload_lds16(gB + k0 + 64 * 1024, lBw + 2048);
    __syncthreads();
    short8 af[4], bf[4];
#pragma unroll
    for (int m = 0; m < 4; ++m)
      af[m] = *(const short8*)&lA[(wr * 64 + m * 16 + (l & 15)) * 32 + (l >> 4) * 8];
#pragma unroll
    for (int n = 0; n < 4; ++n)
      bf[n] = *(const short8*)&lB[(wc * 64 + n * 16 + (l & 15)) * 32 + (l >> 4) * 8];
#pragma unroll
    for (int m = 0; m < 4; ++m)
#pragma unroll
      for (int n = 0; n < 4; ++n)
        acc[m][n] = __builtin_amdgcn_mfma_f32_16x16x32_bf16(af[m], bf[n], acc[m][n], 0, 0, 0);
    __syncthreads();
  }

  if (MODE == 0) {
#pragma unroll
    for (int m = 0; m < 4; ++m) {
      const int row = (int)m0 + wr * 64 + m * 16 + ((l >> 4) << 2);
      const int b = row >> 11, s = row & 2047;
#pragma unroll
      for (int n = 0; n < 4; ++n) {
        const int col = (int)n0 + wc * 64 + n * 16 + (l & 15);
        const int part = col >> 10;
        const int h = (col & 1023) >> 6, d = col & 63;
        const float bv = bias[col];
        const size_t bh = (size_t)(b * 16 + h);
#pragma unroll
        for (int r = 0; r < 4; ++r) {
          const float v = acc[m][n][r] + bv;
          const int ss = s + r;
          if (part == 0)
            qb[(bh * 2048 + ss) * 64 + d] = f32_bf16(v * QSCALE);
          else if (part == 1)
            kb[(bh * 2048 + ss) * 64 + d] = f32_bf16(v);
          else
            vtb[(bh * 64 + d) * 2048 + ss] = f32_bf16(v);  // V transposed
        }
      }
    }
  } else {
#pragma unroll
    for (int m = 0; m < 4; ++m) {
      const size_t row = m0 + wr * 64 + m * 16 + ((l >> 4) << 2);
#pragma unroll
      for (int n = 0; n < 4; ++n) {
        const size_t col = n0 + wc * 64 + n * 16 + (l & 15);
        const float bv = bias[col];
#pragma unroll
        for (int r = 0; r < 4; ++r)
          fout[(row + r) * 1024 + col] = acc[m][n][r] + bv;
      }
    }
  }
}

// ---------------- causal flash attention, swapped-operand, no LDS ----------------
// 1024 blocks x 128 threads; each wave owns 32 q-rows. 32x32x16 MFMAs.
// S^T = mfma(K, Q): lane owns q-column (lane&31); 16 scores/lane per 32-kv tile.
// Softmax fully in-register (one permlane32 exchange per reduce).
// P -> bf16 via v_cvt_pk_bf16_f32 + 4x v_permlane32_swap (T12).
// O^T = mfma(V^T, P^T): lane owns its q's output column; rescale is per-lane scalar.
__global__ __launch_bounds__(128) void attn_fwd2(const u16* __restrict__ Qb,
                                                 const u16* __restrict__ Kb,
                                                 const u16* __restrict__ Vt,
                                                 u16* __restrict__ AO) {
  const int l = threadIdx.x & 63, w = threadIdx.x >> 6;
  const int bid = blockIdx.x;
  // XCD-aware: XCD k serves bh in {4k..4k+3}; heaviest q-tiles dispatch first.
  const int xcd = bid & 7, idx = bid >> 3;
  const int bh = xcd * 4 + (idx & 3);
  const int qb = 31 - (idx >> 2);
  const int j = qb * 2 + w;            // wave q-tile index, 0..63
  const int lq = l & 31, hi = l >> 5;
  const int q = j * 32 + lq;           // q row within S

  const u16* Qh = Qb + (size_t)bh * 2048 * 64;
  const u16* Kh = Kb + (size_t)bh * 2048 * 64;
  const u16* Vh = Vt + (size_t)bh * 64 * 2048;

  // Q B-fragments (col=q=lane&31, k=d=(l>>5)*8+e), 4 mfmas cover D=64
  short8 qf[4];
#pragma unroll
  for (int kk = 0; kk < 4; ++kk)
    qf[kk] = *(const short8*)&Qh[(size_t)q * 64 + kk * 16 + hi * 8];

  f32x16 oA = {}, oB = {};             // O^T cols: d 0..31 / 32..63
  float m = -3.0e38f, lsum = 0.f;

  const u16* Kt0 = Kh + (size_t)lq * 64 + hi * 8;
  const u16* Vt0 = Vh + (size_t)lq * 2048 + hi * 8;

  auto loadK = [&](int kt, short8* kf) {
    const u16* p = Kt0 + (size_t)kt * 2048;   // 32 rows * 64 elems
#pragma unroll
    for (int kk = 0; kk < 4; ++kk) kf[kk] = *(const short8*)&p[kk * 16];
  };
  auto loadV = [&](int kt, short8* vf) {
#pragma unroll
    for (int dh = 0; dh < 2; ++dh)
#pragma unroll
      for (int ks = 0; ks < 2; ++ks)
        vf[dh * 2 + ks] = *(const short8*)&Vt0[(size_t)dh * 32 * 2048 + kt * 32 + ks * 16];
  };

  auto body = [&](const short8* kf, const short8* vf, int kt) {
    // S^T tile: rows = kv (reg pattern), cols = q (lane)
    f32x16 st = {};
#pragma unroll
    for (int kk = 0; kk < 4; ++kk)
      st = __builtin_amdgcn_mfma_f32_32x32x16_bf16(kf[kk], qf[kk], st, 0, 0, 0);

    if (kt == j) {                      // causal mask, diagonal tile only
      const int qm = lq - hi * 4;
#pragma unroll
      for (int r = 0; r < 16; ++r) {
        const int t = (r & 3) + 8 * (r >> 2);
        if (t > qm) st[r] = -3.0e38f;
      }
    }

    // tile max for this q-row: 16 regs + cross-half exchange
    float pm = st[0];
#pragma unroll
    for (int r = 1; r < 16; ++r) pm = fmaxf(pm, st[r]);
    pm = fmaxf(pm, __shfl_xor(pm, 32));

    // defer-max (T13): skip O rescale while max growth <= 8 (exp2 domain)
    if (!__all(pm <= m + 8.0f)) {
      const float mn = fmaxf(m, pm);
      const float alpha = __builtin_amdgcn_exp2f(m - mn);
      lsum *= alpha;
#pragma unroll
      for (int r = 0; r < 16; ++r) { oA[r] *= alpha; oB[r] *= alpha; }
      m = mn;
    }

    float p[16];
    float rs = 0.f;
#pragma unroll
    for (int r = 0; r < 16; ++r) {
      p[r] = __builtin_amdgcn_exp2f(st[r] - m);
      rs += p[r];
    }
    rs += __shfl_xor(rs, 32);
    lsum += rs;

    // pack P to bf16 pairs; pk[j2] covers kv = 8*(j2>>1) + 2*(j2&1) + {0,1} (+4 if hi lane)
    u32 pk[8];
#pragma unroll
    for (int t2 = 0; t2 < 8; ++t2)
      asm("v_cvt_pk_bf16_f32 %0, %1, %2" : "=v"(pk[t2]) : "v"(p[2 * t2]), "v"(p[2 * t2 + 1]));

    // build P^T B-fragments (col=q, k contiguous 8 per half-wave) via half-swaps
    u32 a0 = pk[0], a1 = pk[2]; asm("v_permlane32_swap_b32 %0, %1" : "+v"(a0), "+v"(a1));
    u32 a2 = pk[1], a3 = pk[3]; asm("v_permlane32_swap_b32 %0, %1" : "+v"(a2), "+v"(a3));
    u32 c0 = pk[4], c1 = pk[6]; asm("v_permlane32_swap_b32 %0, %1" : "+v"(c0), "+v"(c1));
    u32 c2 = pk[5], c3 = pk[7]; asm("v_permlane32_swap_b32 %0, %1" : "+v"(c2), "+v"(c3));
    union { u32 u[4]; short8 s; } pf0, pf1;
    pf0.u[0] = a0; pf0.u[1] = a2; pf0.u[2] = a1; pf0.u[3] = a3;  // kv 0..15
    pf1.u[0] = c0; pf1.u[1] = c2; pf1.u[2] = c1; pf1.u[3] = c3;  // kv 16..31

    // O^T += V^T * P^T
    oA = __builtin_amdgcn_mfma_f32_32x32x16_bf16(vf[0], pf0.s, oA, 0, 0, 0);
    oA = __builtin_amdgcn_mfma_f32_32x32x16_bf16(vf[1], pf1.s, oA, 0, 0, 0);
    oB = __builtin_amdgcn_mfma_f32_32x32x16_bf16(vf[2], pf0.s, oB, 0, 0, 0);
    oB = __builtin_amdgcn_mfma_f32_32x32x16_bf16(vf[3], pf1.s, oB, 0, 0, 0);
  };

  // main loop with ping-pong K prefetch (static buffers, rule #20)
  short8 kfA[4], kfB[4], vf[4];
  loadK(0, kfA);
  int kt = 0;
  while (true) {
    loadV(kt, vf);
    loadK(kt + 1 <= j ? kt + 1 : j, kfB);
    body(kfA, vf, kt);
    if (kt == j) break;
    ++kt;
    loadV(kt, vf);
    loadK(kt + 1 <= j ? kt + 1 : j, kfA);
    body(kfB, vf, kt);
    if (kt == j) break;
    ++kt;
  }

  // epilogue: O[q][d] = O^T/lsum, merged-heads AO[b*2048+q][h*64+d]
  const float rl = __builtin_amdgcn_rcpf(lsum);
  const int b = bh >> 4, h = bh & 15;
  u16* orow = AO + ((size_t)(b * 2048 + q)) * 1024 + h * 64;
#pragma unroll
  for (int g = 0; g < 4; ++g) {
    u32 w0, w1, w2, w3;
    float e0 = oA[4 * g] * rl, e1 = oA[4 * g + 1] * rl;
    float e2 = oA[4 * g + 2] * rl, e3 = oA[4 * g + 3] * rl;
    float f0 = oB[4 * g] * rl, f1 = oB[4 * g + 1] * rl;
    float f2 = oB[4 * g + 2] * rl, f3 = oB[4 * g + 3] * rl;
    asm("v_cvt_pk_bf16_f32 %0, %1, %2" : "=v"(w0) : "v"(e0), "v"(e1));
    asm("v_cvt_pk_bf16_f32 %0, %1, %2" : "=v"(w1) : "v"(e2), "v"(e3));
    asm("v_cvt_pk_bf16_f32 %0, %1, %2" : "=v"(w2) : "v"(f0), "v"(f1));
    asm("v_cvt_pk_bf16_f32 %0, %1, %2" : "=v"(w3) : "v"(f2), "v"(f3));
    uint2 uA; uA.x = w0; uA.y = w1;
    uint2 uB; uB.x = w2; uB.y = w3;
    *(uint2*)&orow[8 * g + 4 * hi] = uA;        // d = 8g+4hi .. +3
    *(uint2*)&orow[32 + 8 * g + 4 * hi] = uB;   // d+32
  }
}

// ---------------- launch ----------------

extern "C" void kernel_launch(void* const* d_in, const int* in_sizes, int n_in,
                              void* d_out, int out_size, void* d_ws, size_t ws_size,
                              hipStream_t stream) {
  const float* hs = (const float*)d_in[0];
  const float* w1 = (const float*)d_in[1];
  const float* b1 = (const float*)d_in[2];
  const float* w2 = (const float*)d_in[3];
  const float* b2 = (const float*)d_in[4];
  float* out = (float*)d_out;

  char* ws = (char*)d_ws;
  u16* Xb  = (u16*)(ws);                    // [4096][1024] bf16   (8 MB)
  u16* W1t = (u16*)(ws + (8ull  << 20));    // [3072][1024] bf16   (6 MB)
  u16* W2t = (u16*)(ws + (14ull << 20));    // [1024][1024] bf16   (2 MB)
  u16* Qb  = (u16*)(ws + (16ull << 20));    // [B,H,S,D] bf16      (8 MB)
  u16* Kb  = (u16*)(ws + (24ull << 20));    // [B,H,S,D] bf16      (8 MB)
  u16* Vtb = (u16*)(ws + (32ull << 20));    // [B,H,D,S] bf16      (8 MB)
  u16* AO  = (u16*)(ws + (40ull << 20));    // [4096][1024] bf16   (8 MB)

  cvt_f32_bf16<<<dim3(2048), dim3(256), 0, stream>>>(hs, Xb, 4096 * 1024 / 4);
  transpose_bf16<<<dim3(96, 32), dim3(32, 8), 0, stream>>>(w1, W1t, 1024, 3072);
  transpose_bf16<<<dim3(32, 32), dim3(32, 8), 0, stream>>>(w2, W2t, 1024, 1024);
  gemm_bt<0><<<dim3(24, 32), dim3(256), 0, stream>>>(Xb, W1t, b1, Qb, Kb, Vtb, nullptr);
  attn_fwd2<<<dim3(1024), dim3(128), 0, stream>>>(Qb, Kb, Vtb, AO);
  gemm_bt<1><<<dim3(8, 32), dim3(256), 0, stream>>>(AO, W2t, b2, nullptr, nullptr, nullptr, out);
}

// Round 3
// 147.910 us; speedup vs baseline: 1.4854x; 1.0619x over previous
//
#include <hip/hip_runtime.h>
#include <stdint.h>

// Problem constants: B=2, S=2048, E=1024, H=16, D=64, M = B*S = 4096
#define LOG2E 1.4426950408889634f
#define QSCALE (0.125f * LOG2E)   // fold 1/sqrt(64) and log2(e): softmax in exp2 domain

using u16 = unsigned short;
using u32 = unsigned int;

typedef __attribute__((ext_vector_type(8))) short short8;
typedef __attribute__((ext_vector_type(4))) float f32x4;
typedef __attribute__((ext_vector_type(16))) float f32x16;

__device__ __forceinline__ u16 f32_bf16(float f) {
  union { float f; u32 u; } v; v.f = f;
  u32 u = v.u;
  u += 0x7FFF + ((u >> 16) & 1);   // RNE
  return (u16)(u >> 16);
}

__device__ __forceinline__ void gload_lds16(const void* g, void* l) {
  __builtin_amdgcn_global_load_lds(
      (const __attribute__((address_space(1))) u32*)(uintptr_t)g,
      (__attribute__((address_space(3))) u32*)(u32)(uintptr_t)l, 16, 0, 0);
}

// ---------------- pre-passes ----------------

__global__ __launch_bounds__(256) void cvt_f32_bf16(const float* __restrict__ in,
                                                    u16* __restrict__ out, int n4) {
  for (int i = blockIdx.x * blockDim.x + threadIdx.x; i < n4;
       i += gridDim.x * blockDim.x) {
    float4 v = ((const float4*)in)[i];
    union { u16 h[4]; uint2 u; } o;
    o.h[0] = f32_bf16(v.x); o.h[1] = f32_bf16(v.y);
    o.h[2] = f32_bf16(v.z); o.h[3] = f32_bf16(v.w);
    ((uint2*)out)[i] = o.u;
  }
}

// out[n][k] = bf16(in[k][n]);  in is [K][N] fp32 row-major
__global__ __launch_bounds__(256) void transpose_bf16(const float* __restrict__ in,
                                                      u16* __restrict__ out,
                                                      int K, int N) {
  __shared__ float t[32][33];
  const int n0 = blockIdx.x * 32, k0 = blockIdx.y * 32;
  const int tx = threadIdx.x, ty = threadIdx.y;
#pragma unroll
  for (int j = 0; j < 32; j += 8)
    t[ty + j][tx] = in[(size_t)(k0 + ty + j) * N + n0 + tx];
  __syncthreads();
#pragma unroll
  for (int j = 0; j < 32; j += 8)
    out[(size_t)(n0 + ty + j) * K + k0 + tx] = f32_bf16(t[tx][ty + j]);
}

// ---------------- GEMM: C = A[M,K] * Bt[N,K]^T + bias ----------------
// 128x128 tile, 4 waves (2x2), BK=32, global_load_lds staging (m97 structure).
// MODE 0: QKV epilogue -> scatter to Q[B,H,S,D]*QSCALE, K[B,H,S,D], Vt[B,H,D,S] (bf16)
// MODE 1: fp32 out + bias to fout[M,1024]
template <int MODE>
__global__ __launch_bounds__(256) void gemm_bt(
    const u16* __restrict__ A, const u16* __restrict__ Bt,
    const float* __restrict__ bias,
    u16* __restrict__ qb, u16* __restrict__ kb, u16* __restrict__ vtb,
    float* __restrict__ fout) {
  __shared__ u16 lA[128 * 32];
  __shared__ u16 lB[128 * 32];
  const int tid = threadIdx.x;
  const int w = tid >> 6, l = tid & 63;
  const int bm = blockIdx.y, bn = blockIdx.x;
  const size_t m0 = (size_t)bm * 128, n0 = (size_t)bn * 128;
  const int wr = w >> 1, wc = w & 1;

  f32x4 acc[4][4] = {};

  const int arow = w * 16 + (l >> 2);
  const int acol = (l & 3) * 8;
  const u16* gA = A + (m0 + arow) * 1024 + acol;
  const u16* gB = Bt + (n0 + arow) * 1024 + acol;
  u16* lAw = lA + w * 512;  // HW adds lane*16B
  u16* lBw = lB + w * 512;

  for (int k0 = 0; k0 < 1024; k0 += 32) {
    gload_lds16(gA + k0, lAw);
    gload_lds16(gA + k0 + 64 * 1024, lAw + 2048);
    gload_lds16(gB + k0, lBw);
    gload_lds16(gB + k0 + 64 * 1024, lBw + 2048);
    __syncthreads();
    short8 af[4], bf[4];
#pragma unroll
    for (int m = 0; m < 4; ++m)
      af[m] = *(const short8*)&lA[(wr * 64 + m * 16 + (l & 15)) * 32 + (l >> 4) * 8];
#pragma unroll
    for (int n = 0; n < 4; ++n)
      bf[n] = *(const short8*)&lB[(wc * 64 + n * 16 + (l & 15)) * 32 + (l >> 4) * 8];
#pragma unroll
    for (int m = 0; m < 4; ++m)
#pragma unroll
      for (int n = 0; n < 4; ++n)
        acc[m][n] = __builtin_amdgcn_mfma_f32_16x16x32_bf16(af[m], bf[n], acc[m][n], 0, 0, 0);
    __syncthreads();
  }

  if (MODE == 0) {
#pragma unroll
    for (int m = 0; m < 4; ++m) {
      const int row = (int)m0 + wr * 64 + m * 16 + ((l >> 4) << 2);
      const int b = row >> 11, s = row & 2047;
#pragma unroll
      for (int n = 0; n < 4; ++n) {
        const int col = (int)n0 + wc * 64 + n * 16 + (l & 15);
        const int part = col >> 10;
        const int h = (col & 1023) >> 6, d = col & 63;
        const float bv = bias[col];
        const size_t bh = (size_t)(b * 16 + h);
#pragma unroll
        for (int r = 0; r < 4; ++r) {
          const float v = acc[m][n][r] + bv;
          const int ss = s + r;
          if (part == 0)
            qb[(bh * 2048 + ss) * 64 + d] = f32_bf16(v * QSCALE);
          else if (part == 1)
            kb[(bh * 2048 + ss) * 64 + d] = f32_bf16(v);
          else
            vtb[(bh * 64 + d) * 2048 + ss] = f32_bf16(v);  // V transposed
        }
      }
    }
  } else {
#pragma unroll
    for (int m = 0; m < 4; ++m) {
      const size_t row = m0 + wr * 64 + m * 16 + ((l >> 4) << 2);
#pragma unroll
      for (int n = 0; n < 4; ++n) {
        const size_t col = n0 + wc * 64 + n * 16 + (l & 15);
        const float bv = bias[col];
#pragma unroll
        for (int r = 0; r < 4; ++r)
          fout[(row + r) * 1024 + col] = acc[m][n][r] + bv;
      }
    }
  }
}

// ---------------- causal flash attention, swapped-operand, kv-split-2 ----------------
// 2048 blocks x 128 threads; block = (bh, q-tile of 32 rows); wave w takes kv tiles
// kt = w, w+2, ... Online softmax fully in-register (32x32x16 swapped MFMAs).
// Wave 1 deposits partial O^T/m/l in LDS; wave 0 merges and stores.
__global__ __launch_bounds__(128) void attn_fwd3(const u16* __restrict__ Qb,
                                                 const u16* __restrict__ Kb,
                                                 const u16* __restrict__ Vt,
                                                 u16* __restrict__ AO) {
  __shared__ float o_lds[8][64][4];   // [r4][lane][e] : wave-1 partial O^T
  __shared__ float lm_lds[2][64];     // m, lsum of wave 1
  const int l = threadIdx.x & 63, w = threadIdx.x >> 6;
  const int bid = blockIdx.x;
  // XCD-aware: XCD k serves bh in {4k..4k+3}; heaviest q-tiles dispatch first.
  const int xcd = bid & 7, idx = bid >> 3;
  const int bh = xcd * 4 + (idx & 3);
  const int j = 63 - (idx >> 2);       // q-tile index, 0..63
  const int lq = l & 31, hi = l >> 5;
  const int q = j * 32 + lq;           // q row within S

  const u16* Qh = Qb + (size_t)bh * 2048 * 64;
  const u16* Kh = Kb + (size_t)bh * 2048 * 64;
  const u16* Vh = Vt + (size_t)bh * 64 * 2048;

  // Q B-fragments (col=q=lane&31, k=d=(l>>5)*8+e), 4 mfmas cover D=64
  short8 qf[4];
#pragma unroll
  for (int kk = 0; kk < 4; ++kk)
    qf[kk] = *(const short8*)&Qh[(size_t)q * 64 + kk * 16 + hi * 8];

  f32x16 oA = {}, oB = {};             // O^T cols: d 0..31 / 32..63
  float m = -3.0e38f, lsum = 0.f;

  const u16* Kt0 = Kh + (size_t)lq * 64 + hi * 8;
  const u16* Vt0 = Vh + (size_t)lq * 2048 + hi * 8;

  auto loadK = [&](int kt, short8* kf) {
    const u16* p = Kt0 + (size_t)kt * 2048;   // 32 rows * 64 elems
#pragma unroll
    for (int kk = 0; kk < 4; ++kk) kf[kk] = *(const short8*)&p[kk * 16];
  };
  auto loadV = [&](int kt, short8* vf) {
#pragma unroll
    for (int dh = 0; dh < 2; ++dh)
#pragma unroll
      for (int ks = 0; ks < 2; ++ks)
        vf[dh * 2 + ks] = *(const short8*)&Vt0[(size_t)dh * 32 * 2048 + kt * 32 + ks * 16];
  };

  auto body = [&](const short8* kf, const short8* vf, int kt) {
    // S^T tile: rows = kv (reg pattern), cols = q (lane)
    f32x16 st = {};
    __builtin_amdgcn_s_setprio(1);
#pragma unroll
    for (int kk = 0; kk < 4; ++kk)
      st = __builtin_amdgcn_mfma_f32_32x32x16_bf16(kf[kk], qf[kk], st, 0, 0, 0);
    __builtin_amdgcn_s_setprio(0);

    if (kt == j) {                      // causal mask, diagonal tile only
      const int qm = lq - hi * 4;
#pragma unroll
      for (int r = 0; r < 16; ++r) {
        const int t = (r & 3) + 8 * (r >> 2);
        if (t > qm) st[r] = -3.0e38f;
      }
    }

    // tile max for this q-row: log-depth tree over 16 regs + cross-half exchange
    float x0 = fmaxf(fmaxf(st[0], st[1]), fmaxf(st[2], st[3]));
    float x1 = fmaxf(fmaxf(st[4], st[5]), fmaxf(st[6], st[7]));
    float x2 = fmaxf(fmaxf(st[8], st[9]), fmaxf(st[10], st[11]));
    float x3 = fmaxf(fmaxf(st[12], st[13]), fmaxf(st[14], st[15]));
    float pm = fmaxf(fmaxf(x0, x1), fmaxf(x2, x3));
    pm = fmaxf(pm, __shfl_xor(pm, 32));

    // defer-max (T13): skip O rescale while max growth <= 8 (exp2 domain)
    if (!__all(pm <= m + 8.0f)) {
      const float mn = fmaxf(m, pm);
      const float alpha = __builtin_amdgcn_exp2f(m - mn);
      lsum *= alpha;
#pragma unroll
      for (int r = 0; r < 16; ++r) { oA[r] *= alpha; oB[r] *= alpha; }
      m = mn;
    }

    float p[16];
#pragma unroll
    for (int r = 0; r < 16; ++r) p[r] = __builtin_amdgcn_exp2f(st[r] - m);
    float s0 = (p[0] + p[1]) + (p[2] + p[3]);
    float s1 = (p[4] + p[5]) + (p[6] + p[7]);
    float s2 = (p[8] + p[9]) + (p[10] + p[11]);
    float s3 = (p[12] + p[13]) + (p[14] + p[15]);
    float rs = (s0 + s1) + (s2 + s3);
    rs += __shfl_xor(rs, 32);
    lsum += rs;

    // pack P to bf16 pairs; pk[t2] covers kv = 8*(t2>>1) + 2*(t2&1) + {0,1} (+4 if hi lane)
    u32 pk[8];
#pragma unroll
    for (int t2 = 0; t2 < 8; ++t2)
      asm("v_cvt_pk_bf16_f32 %0, %1, %2" : "=v"(pk[t2]) : "v"(p[2 * t2]), "v"(p[2 * t2 + 1]));

    // build P^T B-fragments (col=q, k contiguous 8 per half-wave) via half-swaps
    u32 a0 = pk[0], a1 = pk[2]; asm("v_permlane32_swap_b32 %0, %1" : "+v"(a0), "+v"(a1));
    u32 a2 = pk[1], a3 = pk[3]; asm("v_permlane32_swap_b32 %0, %1" : "+v"(a2), "+v"(a3));
    u32 c0 = pk[4], c1 = pk[6]; asm("v_permlane32_swap_b32 %0, %1" : "+v"(c0), "+v"(c1));
    u32 c2 = pk[5], c3 = pk[7]; asm("v_permlane32_swap_b32 %0, %1" : "+v"(c2), "+v"(c3));
    union { u32 u[4]; short8 s; } pf0, pf1;
    pf0.u[0] = a0; pf0.u[1] = a2; pf0.u[2] = a1; pf0.u[3] = a3;  // kv 0..15
    pf1.u[0] = c0; pf1.u[1] = c2; pf1.u[2] = c1; pf1.u[3] = c3;  // kv 16..31

    // O^T += V^T * P^T
    __builtin_amdgcn_s_setprio(1);
    oA = __builtin_amdgcn_mfma_f32_32x32x16_bf16(vf[0], pf0.s, oA, 0, 0, 0);
    oA = __builtin_amdgcn_mfma_f32_32x32x16_bf16(vf[1], pf1.s, oA, 0, 0, 0);
    oB = __builtin_amdgcn_mfma_f32_32x32x16_bf16(vf[2], pf0.s, oB, 0, 0, 0);
    oB = __builtin_amdgcn_mfma_f32_32x32x16_bf16(vf[3], pf1.s, oB, 0, 0, 0);
    __builtin_amdgcn_s_setprio(0);
  };

  // main loop: wave w handles kt = w, w+2, ... with ping-pong K prefetch
  if (w <= j) {
    short8 kfA[4], kfB[4], vf[4];
    int kt = w;
    loadK(kt, kfA);
    while (true) {
      loadV(kt, vf);
      loadK(kt + 2 <= j ? kt + 2 : kt, kfB);
      body(kfA, vf, kt);
      if (kt + 2 > j) break;
      kt += 2;
      loadV(kt, vf);
      loadK(kt + 2 <= j ? kt + 2 : kt, kfA);
      body(kfB, vf, kt);
      if (kt + 2 > j) break;
      kt += 2;
    }
  }

  // merge wave partials via LDS
  if (w == 1) {
#pragma unroll
    for (int r4 = 0; r4 < 4; ++r4) {
      f32x4 a = { oA[4 * r4], oA[4 * r4 + 1], oA[4 * r4 + 2], oA[4 * r4 + 3] };
      f32x4 b = { oB[4 * r4], oB[4 * r4 + 1], oB[4 * r4 + 2], oB[4 * r4 + 3] };
      *(f32x4*)&o_lds[r4][l][0] = a;
      *(f32x4*)&o_lds[r4 + 4][l][0] = b;
    }
    lm_lds[0][l] = m;
    lm_lds[1][l] = lsum;
  }
  __syncthreads();
  if (w == 0) {
    const float m1 = lm_lds[0][l], l1 = lm_lds[1][l];
    const float M = fmaxf(m, m1);
    const float sc0 = __builtin_amdgcn_exp2f(m - M);
    const float sc1 = __builtin_amdgcn_exp2f(m1 - M);
    const float L = lsum * sc0 + l1 * sc1;
    const float rl = __builtin_amdgcn_rcpf(L);
    const float a0 = sc0 * rl, a1 = sc1 * rl;
    const int b = bh >> 4, h = bh & 15;
    u16* orow = AO + ((size_t)(b * 2048 + q)) * 1024 + h * 64;
#pragma unroll
    for (int r4 = 0; r4 < 4; ++r4) {
      const f32x4 pa = *(const f32x4*)&o_lds[r4][l][0];
      const f32x4 pb = *(const f32x4*)&o_lds[r4 + 4][l][0];
      float e0 = oA[4 * r4] * a0 + pa[0] * a1;
      float e1 = oA[4 * r4 + 1] * a0 + pa[1] * a1;
      float e2 = oA[4 * r4 + 2] * a0 + pa[2] * a1;
      float e3 = oA[4 * r4 + 3] * a0 + pa[3] * a1;
      float f0 = oB[4 * r4] * a0 + pb[0] * a1;
      float f1 = oB[4 * r4 + 1] * a0 + pb[1] * a1;
      float f2 = oB[4 * r4 + 2] * a0 + pb[2] * a1;
      float f3 = oB[4 * r4 + 3] * a0 + pb[3] * a1;
      u32 w0, w1, w2, w3;
      asm("v_cvt_pk_bf16_f32 %0, %1, %2" : "=v"(w0) : "v"(e0), "v"(e1));
      asm("v_cvt_pk_bf16_f32 %0, %1, %2" : "=v"(w1) : "v"(e2), "v"(e3));
      asm("v_cvt_pk_bf16_f32 %0, %1, %2" : "=v"(w2) : "v"(f0), "v"(f1));
      asm("v_cvt_pk_bf16_f32 %0, %1, %2" : "=v"(w3) : "v"(f2), "v"(f3));
      uint2 uA; uA.x = w0; uA.y = w1;
      uint2 uB; uB.x = w2; uB.y = w3;
      *(uint2*)&orow[8 * r4 + 4 * hi] = uA;        // d = 8*r4+4hi .. +3
      *(uint2*)&orow[32 + 8 * r4 + 4 * hi] = uB;   // d+32
    }
  }
}

// ---------------- launch ----------------

extern "C" void kernel_launch(void* const* d_in, const int* in_sizes, int n_in,
                              void* d_out, int out_size, void* d_ws, size_t ws_size,
                              hipStream_t stream) {
  const float* hs = (const float*)d_in[0];
  const float* w1 = (const float*)d_in[1];
  const float* b1 = (const float*)d_in[2];
  const float* w2 = (const float*)d_in[3];
  const float* b2 = (const float*)d_in[4];
  float* out = (float*)d_out;

  char* ws = (char*)d_ws;
  u16* Xb  = (u16*)(ws);                    // [4096][1024] bf16   (8 MB)
  u16* W1t = (u16*)(ws + (8ull  << 20));    // [3072][1024] bf16   (6 MB)
  u16* W2t = (u16*)(ws + (14ull << 20));    // [1024][1024] bf16   (2 MB)
  u16* Qb  = (u16*)(ws + (16ull << 20));    // [B,H,S,D] bf16      (8 MB)
  u16* Kb  = (u16*)(ws + (24ull << 20));    // [B,H,S,D] bf16      (8 MB)
  u16* Vtb = (u16*)(ws + (32ull << 20));    // [B,H,D,S] bf16      (8 MB)
  u16* AO  = (u16*)(ws + (40ull << 20));    // [4096][1024] bf16   (8 MB)

  cvt_f32_bf16<<<dim3(2048), dim3(256), 0, stream>>>(hs, Xb, 4096 * 1024 / 4);
  transpose_bf16<<<dim3(96, 32), dim3(32, 8), 0, stream>>>(w1, W1t, 1024, 3072);
  transpose_bf16<<<dim3(32, 32), dim3(32, 8), 0, stream>>>(w2, W2t, 1024, 1024);
  gemm_bt<0><<<dim3(24, 32), dim3(256), 0, stream>>>(Xb, W1t, b1, Qb, Kb, Vtb, nullptr);
  attn_fwd3<<<dim3(2048), dim3(128), 0, stream>>>(Qb, Kb, Vtb, AO);
  gemm_bt<1><<<dim3(8, 32), dim3(256), 0, stream>>>(AO, W2t, b2, nullptr, nullptr, nullptr, out);
}